// Round 4
// baseline (1205.144 us; speedup 1.0000x reference)
//
#include <hip/hip_runtime.h>
#include <hip/hip_bf16.h>

#define T_SEQ 2048
#define NH 32
#define NKV 8
#define DH 128

typedef unsigned short u16;
typedef unsigned int u32;
typedef __attribute__((ext_vector_type(8))) short short8;
typedef __attribute__((ext_vector_type(4))) float floatx4;

union U8 { u16 s[8]; uint4 v; };
union F8 { u32 d[4]; short8 s; };

__device__ inline u16 f2bf(float f) {
  __hip_bfloat16 h = __float2bfloat16(f);
  return *reinterpret_cast<u16*>(&h);
}
__device__ inline float bf2f(u16 u) {
  __hip_bfloat16 h;
  *reinterpret_cast<u16*>(&h) = u;
  return __bfloat162float(h);
}

__device__ inline void store_out(float* p, float v) { *p = v; }
__device__ inline void store_out(u16* p, float v) { *p = f2bf(v); }

#define GLD_LDS(g, l) __builtin_amdgcn_global_load_lds( \
    (const __attribute__((address_space(1))) void*)(g), \
    (__attribute__((address_space(3))) void*)(l), 16, 0, 0)

// ---------------- cast x -> bf16 ----------------
__global__ void cast_x_kernel(const float* __restrict__ in, u16* __restrict__ out, int n8) {
  int idx = blockIdx.x * blockDim.x + threadIdx.x;
  if (idx >= n8) return;
  const float4* p = reinterpret_cast<const float4*>(in) + (size_t)idx * 2;
  float4 f0 = p[0], f1 = p[1];
  U8 u;
  u.s[0] = f2bf(f0.x); u.s[1] = f2bf(f0.y); u.s[2] = f2bf(f0.z); u.s[3] = f2bf(f0.w);
  u.s[4] = f2bf(f1.x); u.s[5] = f2bf(f1.y); u.s[6] = f2bf(f1.z); u.s[7] = f2bf(f1.w);
  *reinterpret_cast<uint4*>(out + (size_t)idx * 8) = u.v;
}

// ---------------- transpose + cast: W (K,N) f32 -> WT (N,K) bf16 ----------------
__global__ void transpose_cast_kernel(const float* __restrict__ W, u16* __restrict__ WT,
                                      int K, int N) {
  __shared__ u16 tile[64][72];
  int tid = threadIdx.x;
  int n0 = blockIdx.x * 64, k0 = blockIdx.y * 64;
  int r = tid >> 2, seg = (tid & 3) * 16;
  const float* wp = W + (size_t)(k0 + r) * N + n0 + seg;
#pragma unroll
  for (int jj = 0; jj < 4; ++jj) {
    float4 f = *(const float4*)(wp + jj * 4);
    tile[r][seg + jj * 4 + 0] = f2bf(f.x);
    tile[r][seg + jj * 4 + 1] = f2bf(f.y);
    tile[r][seg + jj * 4 + 2] = f2bf(f.z);
    tile[r][seg + jj * 4 + 3] = f2bf(f.w);
  }
  __syncthreads();
  u16* op = WT + (size_t)(n0 + r) * K + k0 + seg;
#pragma unroll
  for (int jj = 0; jj < 4; ++jj) {
    ushort4 o;
    o.x = tile[seg + jj * 4 + 0][r];
    o.y = tile[seg + jj * 4 + 1][r];
    o.z = tile[seg + jj * 4 + 2][r];
    o.w = tile[seg + jj * 4 + 3][r];
    *(ushort4*)(op + jj * 4) = o;
  }
}

// ---------------- RoPE in place on qkv rows (stride 6144) ----------------
__global__ void rope_kernel(u16* __restrict__ qkv) {
  int idx = blockIdx.x * blockDim.x + threadIdx.x;
  int i = idx & 63;
  int head = (idx >> 6) % 40;
  int row = idx / (64 * 40);
  int t = row & (T_SEQ - 1);
  int col = head < 32 ? head * 128 : 4096 + (head - 32) * 128;
  size_t base = (size_t)row * 6144 + col;
  float x1 = bf2f(qkv[base + i]);
  float x2 = bf2f(qkv[base + 64 + i]);
  float inv = exp2f(-(float)i * (18.931568569324174f / 64.0f));
  float ang = (float)t * inv;
  float c = cosf(ang), s = sinf(ang);
  qkv[base + i]      = f2bf(x1 * c - x2 * s);
  qkv[base + 64 + i] = f2bf(x1 * s + x2 * c);
}

// ---------------- V transpose ----------------
__global__ void vtrans_kernel(const u16* __restrict__ qkv, u16* __restrict__ vt) {
  __shared__ u16 tile[64][72];
  int tid = threadIdx.x;
  int t0 = blockIdx.x * 64, d0 = blockIdx.y * 64, bg = blockIdx.z;
  int b = bg >> 3, g = bg & 7;
  int r = tid >> 2, seg = (tid & 3) * 16;
  const u16* src = qkv + (size_t)(b * T_SEQ + t0 + r) * 6144 + 5120 + g * 128 + d0 + seg;
  *(uint4*)&tile[r][seg] = *(const uint4*)src;
  *(uint4*)&tile[r][seg + 8] = *(const uint4*)(src + 8);
  __syncthreads();
  u16* dst = vt + (size_t)(bg * 128 + d0 + r) * T_SEQ + t0 + seg;
  U8 o0, o1;
#pragma unroll
  for (int e = 0; e < 8; ++e) o0.s[e] = tile[seg + e][r];
#pragma unroll
  for (int e = 0; e < 8; ++e) o1.s[e] = tile[seg + 8 + e][r];
  *(uint4*)dst = o0.v;
  *(uint4*)(dst + 8) = o1.v;
}

// ---------------- GEMM (m97-class, unchanged) ----------------
template <typename OutT>
__global__ __launch_bounds__(256) void gemm_bt(const u16* __restrict__ A,
                                               const u16* __restrict__ B,
                                               OutT* __restrict__ C,
                                               int M, int N, int Kd, int ldc) {
  __shared__ u16 As[128 * 64];
  __shared__ u16 Bs[128 * 64];
  int tid = threadIdx.x;
  int wave = tid >> 6, lane = tid & 63;
  int l15 = lane & 15, quad = lane >> 4;
  int wr = wave >> 1, wc = wave & 1;
  int m0 = blockIdx.y * 128, n0 = blockIdx.x * 128;

  floatx4 acc[4][4];
#pragma unroll
  for (int mt = 0; mt < 4; ++mt)
#pragma unroll
    for (int nt = 0; nt < 4; ++nt)
#pragma unroll
      for (int r = 0; r < 4; ++r) acc[mt][nt][r] = 0.0f;

  int rloc = lane >> 3, slot = lane & 7;
  const u16* agp = A + (size_t)(m0 + wave * 32 + rloc) * Kd + ((slot ^ rloc) * 8);
  const u16* bgp = B + (size_t)(n0 + wave * 32 + rloc) * Kd + ((slot ^ rloc) * 8);
  u16* alp = As + (wave * 32) * 64;
  u16* blp = Bs + (wave * 32) * 64;

  for (int kt = 0; kt < Kd; kt += 64) {
    __syncthreads();
#pragma unroll
    for (int j = 0; j < 4; ++j) {
      GLD_LDS(agp + kt + (size_t)j * 8 * Kd, alp + j * 8 * 64);
      GLD_LDS(bgp + kt + (size_t)j * 8 * Kd, blp + j * 8 * 64);
    }
    __syncthreads();
#pragma unroll
    for (int ks = 0; ks < 2; ++ks) {
      short8 af[4], bfr[4];
      int sl = ((ks * 4 + quad) ^ (l15 & 7)) * 8;
#pragma unroll
      for (int mt = 0; mt < 4; ++mt)
        af[mt] = *(const short8*)&As[(wr * 64 + mt * 16 + l15) * 64 + sl];
#pragma unroll
      for (int nt = 0; nt < 4; ++nt)
        bfr[nt] = *(const short8*)&Bs[(wc * 64 + nt * 16 + l15) * 64 + sl];
#pragma unroll
      for (int mt = 0; mt < 4; ++mt)
#pragma unroll
        for (int nt = 0; nt < 4; ++nt)
          acc[mt][nt] = __builtin_amdgcn_mfma_f32_16x16x32_bf16(af[mt], bfr[nt], acc[mt][nt], 0, 0, 0);
    }
  }

#pragma unroll
  for (int mt = 0; mt < 4; ++mt)
#pragma unroll
    for (int nt = 0; nt < 4; ++nt)
#pragma unroll
      for (int r = 0; r < 4; ++r) {
        int rr = m0 + wr * 64 + mt * 16 + quad * 4 + r;
        int cc = n0 + wc * 64 + nt * 16 + l15;
        store_out(&C[(size_t)rr * ldc + cc], acc[mt][nt][r]);
      }
}

// ---------------- flash attention v5 ----------------
// grid (16, 64). Block bx owns paired 64-row q-tiles {lo=bx, hi=31-bx}; K-tile 64.
// S^T formulation, shfl-assembled P^T, 1-barrier dbuf K staging.
// v5: V read DIRECTLY from global (L2-resident, shared by 64 blocks) — no V LDS
//     staging. LDS 64->32 KiB + __launch_bounds__(256,3) => 3 blocks/CU.
//     setprio removed (hurts in barrier-lockstep blocks). exp2-domain softmax and
//     defer-max (T13) kept.
__device__ inline void softmax_frags(floatx4* sc, float& m_s, float& ell_s,
                                     floatx4* o, F8* pf,
                                     int qglob, int k0, bool diag,
                                     int l15, int quad) {
  const float C = 0.12751553f;  // (1/sqrt(128)) * log2(e)
  float s[4][4];
#pragma unroll
  for (int t4 = 0; t4 < 4; ++t4)
#pragma unroll
    for (int r = 0; r < 4; ++r) {
      float v = sc[t4][r];  // raw (unscaled) score
      if (diag && (k0 + t4 * 16 + quad * 4 + r > qglob)) v = -1e30f;
      s[t4][r] = v;
    }
  // per-q-column max (max over kk): reduce over quads
  float m = s[0][0];
#pragma unroll
  for (int t4 = 0; t4 < 4; ++t4)
#pragma unroll
    for (int r = 0; r < 4; ++r) m = fmaxf(m, s[t4][r]);
  m = fmaxf(m, __shfl_xor(m, 16));
  m = fmaxf(m, __shfl_xor(m, 32));
  // T13 defer-max: skip O/ell rescale while growth <= 90.5 raw units (p <= e^8)
  if (!__all(m <= m_s + 90.5f)) {
    float mnew = fmaxf(m_s, m);
    float alpha = __builtin_amdgcn_exp2f((m_s - mnew) * C);
    m_s = mnew;
    ell_s *= alpha;
#pragma unroll
    for (int dt = 0; dt < 8; ++dt)
#pragma unroll
      for (int r = 0; r < 4; ++r) o[dt][r] *= alpha;
  }
  float mC = m_s * C;
  float sum = 0.f;
#pragma unroll
  for (int t4 = 0; t4 < 4; ++t4)
#pragma unroll
    for (int r = 0; r < 4; ++r) {
      float p = __builtin_amdgcn_exp2f(__builtin_fmaf(s[t4][r], C, -mC));
      s[t4][r] = p;
      sum += p;
    }
  sum += __shfl_xor(sum, 16);
  sum += __shfl_xor(sum, 32);
  ell_s += sum;

  // pack P^T rows into bf16x2 dwords: pk[t4][i] = (p[2i], p[2i+1])
  u32 pk[4][2];
#pragma unroll
  for (int t4 = 0; t4 < 4; ++t4) {
    pk[t4][0] = (u32)f2bf(s[t4][0]) | ((u32)f2bf(s[t4][1]) << 16);
    pk[t4][1] = (u32)f2bf(s[t4][2]) | ((u32)f2bf(s[t4][3]) << 16);
  }
  // assemble B-operand frags: frag[h] elem j = P^T[h*32+quad*8+j][l15]
  int sidxA = (2 * (quad & 1)) * 16 + l15;
  int sidxB = sidxA + 16;
  bool hiq = (quad & 2) != 0;
#pragma unroll
  for (int h = 0; h < 2; ++h) {
    u32 a0 = __shfl((int)pk[2 * h][0], sidxA), b0 = __shfl((int)pk[2 * h + 1][0], sidxA);
    u32 a1 = __shfl((int)pk[2 * h][1], sidxA), b1 = __shfl((int)pk[2 * h + 1][1], sidxA);
    u32 a2 = __shfl((int)pk[2 * h][0], sidxB), b2 = __shfl((int)pk[2 * h + 1][0], sidxB);
    u32 a3 = __shfl((int)pk[2 * h][1], sidxB), b3 = __shfl((int)pk[2 * h + 1][1], sidxB);
    pf[h].d[0] = hiq ? b0 : a0;
    pf[h].d[1] = hiq ? b1 : a1;
    pf[h].d[2] = hiq ? b2 : a2;
    pf[h].d[3] = hiq ? b3 : a3;
  }
}

__global__ __launch_bounds__(256, 3) void attn_kernel(const u16* __restrict__ qkv,
                                                      const u16* __restrict__ vt,
                                                      u16* __restrict__ CTX) {
  const int bx = blockIdx.x;         // 0..15; bx=0 heaviest, dispatched first
  const int bh = blockIdx.y;
  const int b = bh >> 5, h = bh & 31;
  const int g = h >> 2;
  const int bg = b * NKV + g;
  const int tid = threadIdx.x;
  const int w = tid >> 6, lane = tid & 63;
  const int l15 = lane & 15, quad = lane >> 4;
  const int lo = bx, hi = 31 - bx;
  const int niter = hi + 1;

  __shared__ u16 Ks[2 * 64 * 128];   // [kk][d] swizzled, dbuf (32 KiB total)

  const u16* kbase = qkv + (size_t)(b * T_SEQ) * 6144 + 4096 + g * 128;
  const u16* vbase = vt + (size_t)(bg * 128) * T_SEQ;

  // Q B-operand fragments (lane holds q = l15's row)
  short8 aq[2][4];
  const int qg_lo = lo * 64 + w * 16 + l15;
  const int qg_hi = hi * 64 + w * 16 + l15;
  {
    const u16* qp0 = qkv + (size_t)(b * T_SEQ + qg_lo) * 6144 + h * 128;
    const u16* qp1 = qkv + (size_t)(b * T_SEQ + qg_hi) * 6144 + h * 128;
#pragma unroll
    for (int ks = 0; ks < 4; ++ks) {
      aq[0][ks] = *(const short8*)(qp0 + ks * 32 + quad * 8);
      aq[1][ks] = *(const short8*)(qp1 + ks * 32 + quad * 8);
    }
  }

  float m_s[2] = {-1e30f, -1e30f}, ell[2] = {0.f, 0.f};
  floatx4 o[2][8];
#pragma unroll
  for (int t = 0; t < 2; ++t)
#pragma unroll
    for (int dt = 0; dt < 8; ++dt)
#pragma unroll
      for (int r = 0; r < 4; ++r) o[t][dt][r] = 0.0f;

  // K staging lane roles
  const int krloc = lane >> 4, kslot = lane & 15;

  // prologue: stage K tile 0 into buf 0
  {
#pragma unroll
    for (int j = 0; j < 4; ++j) {
      int rk = w * 16 + j * 4 + krloc;
      int gck = (kslot & 8) | ((kslot & 7) ^ (rk & 7));
      GLD_LDS(kbase + (size_t)rk * 6144 + gck * 8, Ks + (w * 16 + j * 4) * 128);
    }
  }

  for (int kt = 0; kt < niter; ++kt) {
    const int buf = kt & 1;
    const int k0 = kt * 64;
    __syncthreads();  // K stage(kt) complete; all waves done reading buf^1 from kt-1

    if (kt + 1 < niter) {  // prefetch K(kt+1) into buf^1, overlapped with compute(kt)
      const int nb = buf ^ 1;
      const int k0n = k0 + 64;
#pragma unroll
      for (int j = 0; j < 4; ++j) {
        int rk = w * 16 + j * 4 + krloc;
        int gck = (kslot & 8) | ((kslot & 7) ^ (rk & 7));
        GLD_LDS(kbase + (size_t)(k0n + rk) * 6144 + gck * 8,
                Ks + nb * 8192 + (w * 16 + j * 4) * 128);
      }
    }

    const u16* Ksb = Ks + buf * 8192;
    const bool lo_on = (kt <= lo);

    // S^T = K Q^T
    floatx4 s0[4], s1[4];
#pragma unroll
    for (int t4 = 0; t4 < 4; ++t4)
#pragma unroll
      for (int r = 0; r < 4; ++r) { s0[t4][r] = 0.f; s1[t4][r] = 0.f; }

    if (lo_on) {
#pragma unroll
      for (int ks = 0; ks < 4; ++ks) {
        int c = ks * 4 + quad;
        int sl = ((c & 8) | ((c & 7) ^ (l15 & 7))) * 8;
#pragma unroll
        for (int t4 = 0; t4 < 4; ++t4) {
          short8 bk = *(const short8*)&Ksb[(t4 * 16 + l15) * 128 + sl];
          s1[t4] = __builtin_amdgcn_mfma_f32_16x16x32_bf16(bk, aq[1][ks], s1[t4], 0, 0, 0);
          s0[t4] = __builtin_amdgcn_mfma_f32_16x16x32_bf16(bk, aq[0][ks], s0[t4], 0, 0, 0);
        }
      }
    } else {
#pragma unroll
      for (int ks = 0; ks < 4; ++ks) {
        int c = ks * 4 + quad;
        int sl = ((c & 8) | ((c & 7) ^ (l15 & 7))) * 8;
#pragma unroll
        for (int t4 = 0; t4 < 4; ++t4) {
          short8 bk = *(const short8*)&Ksb[(t4 * 16 + l15) * 128 + sl];
          s1[t4] = __builtin_amdgcn_mfma_f32_16x16x32_bf16(bk, aq[1][ks], s1[t4], 0, 0, 0);
        }
      }
    }

    // softmax for both tiles -> P^T fragments
    F8 pf1[2], pf0[2];
    softmax_frags(s1, m_s[1], ell[1], o[1], pf1, qg_hi, k0, kt == hi, l15, quad);
    if (lo_on)
      softmax_frags(s0, m_s[0], ell[0], o[0], pf0, qg_lo, k0, kt == lo, l15, quad);

    // fused PV: O^T += V^T P^T; V^T fragments read directly from global (L2-hot),
    // one read shared by both q-tiles. lane reads V^T[dt*16+l15][k0 + quad*8 (+32)].
    const u16* vp0 = vbase + (size_t)l15 * T_SEQ + k0 + quad * 8;
    if (lo_on) {
#pragma unroll
      for (int dt = 0; dt < 8; ++dt) {
        const u16* vp = vp0 + (size_t)(dt * 16) * T_SEQ;
        short8 va0 = *(const short8*)vp;
        short8 va1 = *(const short8*)(vp + 32);
        o[1][dt] = __builtin_amdgcn_mfma_f32_16x16x32_bf16(va0, pf1[0].s, o[1][dt], 0, 0, 0);
        o[1][dt] = __builtin_amdgcn_mfma_f32_16x16x32_bf16(va1, pf1[1].s, o[1][dt], 0, 0, 0);
        o[0][dt] = __builtin_amdgcn_mfma_f32_16x16x32_bf16(va0, pf0[0].s, o[0][dt], 0, 0, 0);
        o[0][dt] = __builtin_amdgcn_mfma_f32_16x16x32_bf16(va1, pf0[1].s, o[0][dt], 0, 0, 0);
      }
    } else {
#pragma unroll
      for (int dt = 0; dt < 8; ++dt) {
        const u16* vp = vp0 + (size_t)(dt * 16) * T_SEQ;
        short8 va0 = *(const short8*)vp;
        short8 va1 = *(const short8*)(vp + 32);
        o[1][dt] = __builtin_amdgcn_mfma_f32_16x16x32_bf16(va0, pf1[0].s, o[1][dt], 0, 0, 0);
        o[1][dt] = __builtin_amdgcn_mfma_f32_16x16x32_bf16(va1, pf1[1].s, o[1][dt], 0, 0, 0);
      }
    }
  }

  // epilogue: O^T -> ctx (lane q = l15; 4 consecutive d per dt)
#pragma unroll
  for (int t = 0; t < 2; ++t) {
    float inv_l = 1.0f / ell[t];
    int qglob = (t ? qg_hi : qg_lo);
    u16* cp = CTX + (size_t)(b * T_SEQ + qglob) * 4096 + h * 128 + quad * 4;
#pragma unroll
    for (int dt = 0; dt < 8; ++dt) {
      ushort4 pkd;
      pkd.x = f2bf(o[t][dt][0] * inv_l);
      pkd.y = f2bf(o[t][dt][1] * inv_l);
      pkd.z = f2bf(o[t][dt][2] * inv_l);
      pkd.w = f2bf(o[t][dt][3] * inv_l);
      *(ushort4*)(cp + dt * 16) = pkd;
    }
  }
}

// ---------------- launcher ----------------
extern "C" void kernel_launch(void* const* d_in, const int* in_sizes, int n_in,
                              void* d_out, int out_size, void* d_ws, size_t ws_size,
                              hipStream_t stream) {
  const float* x  = (const float*)d_in[0];
  const float* Wq = (const float*)d_in[1];
  const float* Wk = (const float*)d_in[2];
  const float* Wv = (const float*)d_in[3];
  const float* Wo = (const float*)d_in[4];
  float* out = (float*)d_out;

  char* ws = (char*)d_ws;
  const size_t SZ_X    = (size_t)4096 * 4096 * 2;
  const size_t SZ_QKVW = (size_t)6144 * 4096 * 2;
  u16* xb    = (u16*)(ws);
  u16* wqkvT = (u16*)(ws + SZ_X);
  u16* woT   = (u16*)(ws + SZ_X + SZ_QKVW);
  u16* qkv   = (u16*)(ws + SZ_X + SZ_QKVW + SZ_X);
  u16* vt    = (u16*)(ws + SZ_X + SZ_QKVW + SZ_X + SZ_QKVW);
  u16* ctx   = xb;  // x dead after QKV GEMM

  cast_x_kernel<<<8192, 256, 0, stream>>>(x, xb, 2097152);
  transpose_cast_kernel<<<dim3(64, 64), 256, 0, stream>>>(Wq, wqkvT, 4096, 4096);
  transpose_cast_kernel<<<dim3(16, 64), 256, 0, stream>>>(Wk, wqkvT + (size_t)4096 * 4096, 4096, 1024);
  transpose_cast_kernel<<<dim3(16, 64), 256, 0, stream>>>(Wv, wqkvT + (size_t)5120 * 4096, 4096, 1024);
  transpose_cast_kernel<<<dim3(64, 64), 256, 0, stream>>>(Wo, woT, 4096, 4096);

  gemm_bt<u16><<<dim3(48, 32), 256, 0, stream>>>(xb, wqkvT, qkv, 4096, 6144, 4096, 6144);

  rope_kernel<<<40960, 256, 0, stream>>>(qkv);
  vtrans_kernel<<<dim3(32, 2, 16), 256, 0, stream>>>(qkv, vt);

  attn_kernel<<<dim3(16, 64), 256, 0, stream>>>(qkv, vt, ctx);

  gemm_bt<float><<<dim3(32, 32), 256, 0, stream>>>(ctx, woT, out, 4096, 4096, 4096, 4096);
}

// Round 5
// 947.814 us; speedup vs baseline: 1.2715x; 1.2715x over previous
//
#include <hip/hip_runtime.h>
#include <hip/hip_bf16.h>

#define T_SEQ 2048
#define NH 32
#define NKV 8
#define DH 128

typedef unsigned short u16;
typedef unsigned int u32;
typedef __attribute__((ext_vector_type(8))) short short8;
typedef __attribute__((ext_vector_type(4))) float floatx4;

union U8 { u16 s[8]; uint4 v; };
union F8 { u32 d[4]; short8 s; };

__device__ inline u16 f2bf(float f) {
  __hip_bfloat16 h = __float2bfloat16(f);
  return *reinterpret_cast<u16*>(&h);
}
__device__ inline float bf2f(u16 u) {
  __hip_bfloat16 h;
  *reinterpret_cast<u16*>(&h) = u;
  return __bfloat162float(h);
}

__device__ inline void store_out(float* p, float v) { *p = v; }
__device__ inline void store_out(u16* p, float v) { *p = f2bf(v); }

#define GLD_LDS(g, l) __builtin_amdgcn_global_load_lds( \
    (const __attribute__((address_space(1))) void*)(g), \
    (__attribute__((address_space(3))) void*)(l), 16, 0, 0)

// ---------------- cast x -> bf16 ----------------
__global__ void cast_x_kernel(const float* __restrict__ in, u16* __restrict__ out, int n8) {
  int idx = blockIdx.x * blockDim.x + threadIdx.x;
  if (idx >= n8) return;
  const float4* p = reinterpret_cast<const float4*>(in) + (size_t)idx * 2;
  float4 f0 = p[0], f1 = p[1];
  U8 u;
  u.s[0] = f2bf(f0.x); u.s[1] = f2bf(f0.y); u.s[2] = f2bf(f0.z); u.s[3] = f2bf(f0.w);
  u.s[4] = f2bf(f1.x); u.s[5] = f2bf(f1.y); u.s[6] = f2bf(f1.z); u.s[7] = f2bf(f1.w);
  *reinterpret_cast<uint4*>(out + (size_t)idx * 8) = u.v;
}

// ---------------- transpose + cast: W (K,N) f32 -> WT (N,K) bf16 ----------------
__global__ void transpose_cast_kernel(const float* __restrict__ W, u16* __restrict__ WT,
                                      int K, int N) {
  __shared__ u16 tile[64][72];
  int tid = threadIdx.x;
  int n0 = blockIdx.x * 64, k0 = blockIdx.y * 64;
  int r = tid >> 2, seg = (tid & 3) * 16;
  const float* wp = W + (size_t)(k0 + r) * N + n0 + seg;
#pragma unroll
  for (int jj = 0; jj < 4; ++jj) {
    float4 f = *(const float4*)(wp + jj * 4);
    tile[r][seg + jj * 4 + 0] = f2bf(f.x);
    tile[r][seg + jj * 4 + 1] = f2bf(f.y);
    tile[r][seg + jj * 4 + 2] = f2bf(f.z);
    tile[r][seg + jj * 4 + 3] = f2bf(f.w);
  }
  __syncthreads();
  u16* op = WT + (size_t)(n0 + r) * K + k0 + seg;
#pragma unroll
  for (int jj = 0; jj < 4; ++jj) {
    ushort4 o;
    o.x = tile[seg + jj * 4 + 0][r];
    o.y = tile[seg + jj * 4 + 1][r];
    o.z = tile[seg + jj * 4 + 2][r];
    o.w = tile[seg + jj * 4 + 3][r];
    *(ushort4*)(op + jj * 4) = o;
  }
}

// ---------------- RoPE in place on qkv rows (stride 6144) ----------------
__global__ void rope_kernel(u16* __restrict__ qkv) {
  int idx = blockIdx.x * blockDim.x + threadIdx.x;
  int i = idx & 63;
  int head = (idx >> 6) % 40;
  int row = idx / (64 * 40);
  int t = row & (T_SEQ - 1);
  int col = head < 32 ? head * 128 : 4096 + (head - 32) * 128;
  size_t base = (size_t)row * 6144 + col;
  float x1 = bf2f(qkv[base + i]);
  float x2 = bf2f(qkv[base + 64 + i]);
  float inv = exp2f(-(float)i * (18.931568569324174f / 64.0f));
  float ang = (float)t * inv;
  float c = cosf(ang), s = sinf(ang);
  qkv[base + i]      = f2bf(x1 * c - x2 * s);
  qkv[base + 64 + i] = f2bf(x1 * s + x2 * c);
}

// ---------------- V transpose ----------------
__global__ void vtrans_kernel(const u16* __restrict__ qkv, u16* __restrict__ vt) {
  __shared__ u16 tile[64][72];
  int tid = threadIdx.x;
  int t0 = blockIdx.x * 64, d0 = blockIdx.y * 64, bg = blockIdx.z;
  int b = bg >> 3, g = bg & 7;
  int r = tid >> 2, seg = (tid & 3) * 16;
  const u16* src = qkv + (size_t)(b * T_SEQ + t0 + r) * 6144 + 5120 + g * 128 + d0 + seg;
  *(uint4*)&tile[r][seg] = *(const uint4*)src;
  *(uint4*)&tile[r][seg + 8] = *(const uint4*)(src + 8);
  __syncthreads();
  u16* dst = vt + (size_t)(bg * 128 + d0 + r) * T_SEQ + t0 + seg;
  U8 o0, o1;
#pragma unroll
  for (int e = 0; e < 8; ++e) o0.s[e] = tile[seg + e][r];
#pragma unroll
  for (int e = 0; e < 8; ++e) o1.s[e] = tile[seg + 8 + e][r];
  *(uint4*)dst = o0.v;
  *(uint4*)(dst + 8) = o1.v;
}

// ---------------- GEMM (m97-class, unchanged) ----------------
template <typename OutT>
__global__ __launch_bounds__(256) void gemm_bt(const u16* __restrict__ A,
                                               const u16* __restrict__ B,
                                               OutT* __restrict__ C,
                                               int M, int N, int Kd, int ldc) {
  __shared__ u16 As[128 * 64];
  __shared__ u16 Bs[128 * 64];
  int tid = threadIdx.x;
  int wave = tid >> 6, lane = tid & 63;
  int l15 = lane & 15, quad = lane >> 4;
  int wr = wave >> 1, wc = wave & 1;
  int m0 = blockIdx.y * 128, n0 = blockIdx.x * 128;

  floatx4 acc[4][4];
#pragma unroll
  for (int mt = 0; mt < 4; ++mt)
#pragma unroll
    for (int nt = 0; nt < 4; ++nt)
#pragma unroll
      for (int r = 0; r < 4; ++r) acc[mt][nt][r] = 0.0f;

  int rloc = lane >> 3, slot = lane & 7;
  const u16* agp = A + (size_t)(m0 + wave * 32 + rloc) * Kd + ((slot ^ rloc) * 8);
  const u16* bgp = B + (size_t)(n0 + wave * 32 + rloc) * Kd + ((slot ^ rloc) * 8);
  u16* alp = As + (wave * 32) * 64;
  u16* blp = Bs + (wave * 32) * 64;

  for (int kt = 0; kt < Kd; kt += 64) {
    __syncthreads();
#pragma unroll
    for (int j = 0; j < 4; ++j) {
      GLD_LDS(agp + kt + (size_t)j * 8 * Kd, alp + j * 8 * 64);
      GLD_LDS(bgp + kt + (size_t)j * 8 * Kd, blp + j * 8 * 64);
    }
    __syncthreads();
#pragma unroll
    for (int ks = 0; ks < 2; ++ks) {
      short8 af[4], bfr[4];
      int sl = ((ks * 4 + quad) ^ (l15 & 7)) * 8;
#pragma unroll
      for (int mt = 0; mt < 4; ++mt)
        af[mt] = *(const short8*)&As[(wr * 64 + mt * 16 + l15) * 64 + sl];
#pragma unroll
      for (int nt = 0; nt < 4; ++nt)
        bfr[nt] = *(const short8*)&Bs[(wc * 64 + nt * 16 + l15) * 64 + sl];
#pragma unroll
      for (int mt = 0; mt < 4; ++mt)
#pragma unroll
        for (int nt = 0; nt < 4; ++nt)
          acc[mt][nt] = __builtin_amdgcn_mfma_f32_16x16x32_bf16(af[mt], bfr[nt], acc[mt][nt], 0, 0, 0);
    }
  }

#pragma unroll
  for (int mt = 0; mt < 4; ++mt)
#pragma unroll
    for (int nt = 0; nt < 4; ++nt)
#pragma unroll
      for (int r = 0; r < 4; ++r) {
        int rr = m0 + wr * 64 + mt * 16 + quad * 4 + r;
        int cc = n0 + wc * 64 + nt * 16 + l15;
        store_out(&C[(size_t)rr * ldc + cc], acc[mt][nt][r]);
      }
}

// ---------------- flash attention v6 ----------------
// grid (16, 64). Block bx owns paired 64-row q-tiles {lo=bx, hi=31-bx}; K-tile 64.
// S^T formulation, shfl-assembled P^T, 1-barrier dbuf K staging.
// v6: v5 (V direct from global, 32 KiB LDS) but launch_bounds(256,2) — v5's
//     (256,3) forced VGPR to 84 and spilled the o[] accumulators to scratch
//     (WRITE_SIZE 32->253 MB). Natural ~160 VGPR => 3 blocks/CU via LDS anyway.
__device__ inline void softmax_frags(floatx4* sc, float& m_s, float& ell_s,
                                     floatx4* o, F8* pf,
                                     int qglob, int k0, bool diag,
                                     int l15, int quad) {
  const float C = 0.12751553f;  // (1/sqrt(128)) * log2(e)
  float s[4][4];
#pragma unroll
  for (int t4 = 0; t4 < 4; ++t4)
#pragma unroll
    for (int r = 0; r < 4; ++r) {
      float v = sc[t4][r];  // raw (unscaled) score
      if (diag && (k0 + t4 * 16 + quad * 4 + r > qglob)) v = -1e30f;
      s[t4][r] = v;
    }
  // per-q-column max (max over kk): reduce over quads
  float m = s[0][0];
#pragma unroll
  for (int t4 = 0; t4 < 4; ++t4)
#pragma unroll
    for (int r = 0; r < 4; ++r) m = fmaxf(m, s[t4][r]);
  m = fmaxf(m, __shfl_xor(m, 16));
  m = fmaxf(m, __shfl_xor(m, 32));
  // T13 defer-max: skip O/ell rescale while growth <= 90.5 raw units (p <= e^8)
  if (!__all(m <= m_s + 90.5f)) {
    float mnew = fmaxf(m_s, m);
    float alpha = __builtin_amdgcn_exp2f((m_s - mnew) * C);
    m_s = mnew;
    ell_s *= alpha;
#pragma unroll
    for (int dt = 0; dt < 8; ++dt)
#pragma unroll
      for (int r = 0; r < 4; ++r) o[dt][r] *= alpha;
  }
  float mC = m_s * C;
  float sum = 0.f;
#pragma unroll
  for (int t4 = 0; t4 < 4; ++t4)
#pragma unroll
    for (int r = 0; r < 4; ++r) {
      float p = __builtin_amdgcn_exp2f(__builtin_fmaf(s[t4][r], C, -mC));
      s[t4][r] = p;
      sum += p;
    }
  sum += __shfl_xor(sum, 16);
  sum += __shfl_xor(sum, 32);
  ell_s += sum;

  // pack P^T rows into bf16x2 dwords: pk[t4][i] = (p[2i], p[2i+1])
  u32 pk[4][2];
#pragma unroll
  for (int t4 = 0; t4 < 4; ++t4) {
    pk[t4][0] = (u32)f2bf(s[t4][0]) | ((u32)f2bf(s[t4][1]) << 16);
    pk[t4][1] = (u32)f2bf(s[t4][2]) | ((u32)f2bf(s[t4][3]) << 16);
  }
  // assemble B-operand frags: frag[h] elem j = P^T[h*32+quad*8+j][l15]
  int sidxA = (2 * (quad & 1)) * 16 + l15;
  int sidxB = sidxA + 16;
  bool hiq = (quad & 2) != 0;
#pragma unroll
  for (int h = 0; h < 2; ++h) {
    u32 a0 = __shfl((int)pk[2 * h][0], sidxA), b0 = __shfl((int)pk[2 * h + 1][0], sidxA);
    u32 a1 = __shfl((int)pk[2 * h][1], sidxA), b1 = __shfl((int)pk[2 * h + 1][1], sidxA);
    u32 a2 = __shfl((int)pk[2 * h][0], sidxB), b2 = __shfl((int)pk[2 * h + 1][0], sidxB);
    u32 a3 = __shfl((int)pk[2 * h][1], sidxB), b3 = __shfl((int)pk[2 * h + 1][1], sidxB);
    pf[h].d[0] = hiq ? b0 : a0;
    pf[h].d[1] = hiq ? b1 : a1;
    pf[h].d[2] = hiq ? b2 : a2;
    pf[h].d[3] = hiq ? b3 : a3;
  }
}

__global__ __launch_bounds__(256, 2) void attn_kernel(const u16* __restrict__ qkv,
                                                      const u16* __restrict__ vt,
                                                      u16* __restrict__ CTX) {
  const int bx = blockIdx.x;         // 0..15; bx=0 heaviest, dispatched first
  const int bh = blockIdx.y;
  const int b = bh >> 5, h = bh & 31;
  const int g = h >> 2;
  const int bg = b * NKV + g;
  const int tid = threadIdx.x;
  const int w = tid >> 6, lane = tid & 63;
  const int l15 = lane & 15, quad = lane >> 4;
  const int lo = bx, hi = 31 - bx;
  const int niter = hi + 1;

  __shared__ u16 Ks[2 * 64 * 128];   // [kk][d] swizzled, dbuf (32 KiB total)

  const u16* kbase = qkv + (size_t)(b * T_SEQ) * 6144 + 4096 + g * 128;
  const u16* vbase = vt + (size_t)(bg * 128) * T_SEQ;

  // Q B-operand fragments (lane holds q = l15's row)
  short8 aq[2][4];
  const int qg_lo = lo * 64 + w * 16 + l15;
  const int qg_hi = hi * 64 + w * 16 + l15;
  {
    const u16* qp0 = qkv + (size_t)(b * T_SEQ + qg_lo) * 6144 + h * 128;
    const u16* qp1 = qkv + (size_t)(b * T_SEQ + qg_hi) * 6144 + h * 128;
#pragma unroll
    for (int ks = 0; ks < 4; ++ks) {
      aq[0][ks] = *(const short8*)(qp0 + ks * 32 + quad * 8);
      aq[1][ks] = *(const short8*)(qp1 + ks * 32 + quad * 8);
    }
  }

  float m_s[2] = {-1e30f, -1e30f}, ell[2] = {0.f, 0.f};
  floatx4 o[2][8];
#pragma unroll
  for (int t = 0; t < 2; ++t)
#pragma unroll
    for (int dt = 0; dt < 8; ++dt)
#pragma unroll
      for (int r = 0; r < 4; ++r) o[t][dt][r] = 0.0f;

  // K staging lane roles
  const int krloc = lane >> 4, kslot = lane & 15;

  // prologue: stage K tile 0 into buf 0
  {
#pragma unroll
    for (int j = 0; j < 4; ++j) {
      int rk = w * 16 + j * 4 + krloc;
      int gck = (kslot & 8) | ((kslot & 7) ^ (rk & 7));
      GLD_LDS(kbase + (size_t)rk * 6144 + gck * 8, Ks + (w * 16 + j * 4) * 128);
    }
  }

  for (int kt = 0; kt < niter; ++kt) {
    const int buf = kt & 1;
    const int k0 = kt * 64;
    __syncthreads();  // K stage(kt) complete; all waves done reading buf^1 from kt-1

    if (kt + 1 < niter) {  // prefetch K(kt+1) into buf^1, overlapped with compute(kt)
      const int nb = buf ^ 1;
      const int k0n = k0 + 64;
#pragma unroll
      for (int j = 0; j < 4; ++j) {
        int rk = w * 16 + j * 4 + krloc;
        int gck = (kslot & 8) | ((kslot & 7) ^ (rk & 7));
        GLD_LDS(kbase + (size_t)(k0n + rk) * 6144 + gck * 8,
                Ks + nb * 8192 + (w * 16 + j * 4) * 128);
      }
    }

    const u16* Ksb = Ks + buf * 8192;
    const bool lo_on = (kt <= lo);

    // S^T = K Q^T
    floatx4 s0[4], s1[4];
#pragma unroll
    for (int t4 = 0; t4 < 4; ++t4)
#pragma unroll
      for (int r = 0; r < 4; ++r) { s0[t4][r] = 0.f; s1[t4][r] = 0.f; }

    if (lo_on) {
#pragma unroll
      for (int ks = 0; ks < 4; ++ks) {
        int c = ks * 4 + quad;
        int sl = ((c & 8) | ((c & 7) ^ (l15 & 7))) * 8;
#pragma unroll
        for (int t4 = 0; t4 < 4; ++t4) {
          short8 bk = *(const short8*)&Ksb[(t4 * 16 + l15) * 128 + sl];
          s1[t4] = __builtin_amdgcn_mfma_f32_16x16x32_bf16(bk, aq[1][ks], s1[t4], 0, 0, 0);
          s0[t4] = __builtin_amdgcn_mfma_f32_16x16x32_bf16(bk, aq[0][ks], s0[t4], 0, 0, 0);
        }
      }
    } else {
#pragma unroll
      for (int ks = 0; ks < 4; ++ks) {
        int c = ks * 4 + quad;
        int sl = ((c & 8) | ((c & 7) ^ (l15 & 7))) * 8;
#pragma unroll
        for (int t4 = 0; t4 < 4; ++t4) {
          short8 bk = *(const short8*)&Ksb[(t4 * 16 + l15) * 128 + sl];
          s1[t4] = __builtin_amdgcn_mfma_f32_16x16x32_bf16(bk, aq[1][ks], s1[t4], 0, 0, 0);
        }
      }
    }

    // softmax for both tiles -> P^T fragments
    F8 pf1[2], pf0[2];
    softmax_frags(s1, m_s[1], ell[1], o[1], pf1, qg_hi, k0, kt == hi, l15, quad);
    if (lo_on)
      softmax_frags(s0, m_s[0], ell[0], o[0], pf0, qg_lo, k0, kt == lo, l15, quad);

    // fused PV: O^T += V^T P^T; V^T fragments read directly from global (L2-hot),
    // one read shared by both q-tiles. lane reads V^T[dt*16+l15][k0 + quad*8 (+32)].
    const u16* vp0 = vbase + (size_t)l15 * T_SEQ + k0 + quad * 8;
    if (lo_on) {
#pragma unroll
      for (int dt = 0; dt < 8; ++dt) {
        const u16* vp = vp0 + (size_t)(dt * 16) * T_SEQ;
        short8 va0 = *(const short8*)vp;
        short8 va1 = *(const short8*)(vp + 32);
        o[1][dt] = __builtin_amdgcn_mfma_f32_16x16x32_bf16(va0, pf1[0].s, o[1][dt], 0, 0, 0);
        o[1][dt] = __builtin_amdgcn_mfma_f32_16x16x32_bf16(va1, pf1[1].s, o[1][dt], 0, 0, 0);
        o[0][dt] = __builtin_amdgcn_mfma_f32_16x16x32_bf16(va0, pf0[0].s, o[0][dt], 0, 0, 0);
        o[0][dt] = __builtin_amdgcn_mfma_f32_16x16x32_bf16(va1, pf0[1].s, o[0][dt], 0, 0, 0);
      }
    } else {
#pragma unroll
      for (int dt = 0; dt < 8; ++dt) {
        const u16* vp = vp0 + (size_t)(dt * 16) * T_SEQ;
        short8 va0 = *(const short8*)vp;
        short8 va1 = *(const short8*)(vp + 32);
        o[1][dt] = __builtin_amdgcn_mfma_f32_16x16x32_bf16(va0, pf1[0].s, o[1][dt], 0, 0, 0);
        o[1][dt] = __builtin_amdgcn_mfma_f32_16x16x32_bf16(va1, pf1[1].s, o[1][dt], 0, 0, 0);
      }
    }
  }

  // epilogue: O^T -> ctx (lane q = l15; 4 consecutive d per dt)
#pragma unroll
  for (int t = 0; t < 2; ++t) {
    float inv_l = 1.0f / ell[t];
    int qglob = (t ? qg_hi : qg_lo);
    u16* cp = CTX + (size_t)(b * T_SEQ + qglob) * 4096 + h * 128 + quad * 4;
#pragma unroll
    for (int dt = 0; dt < 8; ++dt) {
      ushort4 pkd;
      pkd.x = f2bf(o[t][dt][0] * inv_l);
      pkd.y = f2bf(o[t][dt][1] * inv_l);
      pkd.z = f2bf(o[t][dt][2] * inv_l);
      pkd.w = f2bf(o[t][dt][3] * inv_l);
      *(ushort4*)(cp + dt * 16) = pkd;
    }
  }
}

// ---------------- launcher ----------------
extern "C" void kernel_launch(void* const* d_in, const int* in_sizes, int n_in,
                              void* d_out, int out_size, void* d_ws, size_t ws_size,
                              hipStream_t stream) {
  const float* x  = (const float*)d_in[0];
  const float* Wq = (const float*)d_in[1];
  const float* Wk = (const float*)d_in[2];
  const float* Wv = (const float*)d_in[3];
  const float* Wo = (const float*)d_in[4];
  float* out = (float*)d_out;

  char* ws = (char*)d_ws;
  const size_t SZ_X    = (size_t)4096 * 4096 * 2;
  const size_t SZ_QKVW = (size_t)6144 * 4096 * 2;
  u16* xb    = (u16*)(ws);
  u16* wqkvT = (u16*)(ws + SZ_X);
  u16* woT   = (u16*)(ws + SZ_X + SZ_QKVW);
  u16* qkv   = (u16*)(ws + SZ_X + SZ_QKVW + SZ_X);
  u16* vt    = (u16*)(ws + SZ_X + SZ_QKVW + SZ_X + SZ_QKVW);
  u16* ctx   = xb;  // x dead after QKV GEMM

  cast_x_kernel<<<8192, 256, 0, stream>>>(x, xb, 2097152);
  transpose_cast_kernel<<<dim3(64, 64), 256, 0, stream>>>(Wq, wqkvT, 4096, 4096);
  transpose_cast_kernel<<<dim3(16, 64), 256, 0, stream>>>(Wk, wqkvT + (size_t)4096 * 4096, 4096, 1024);
  transpose_cast_kernel<<<dim3(16, 64), 256, 0, stream>>>(Wv, wqkvT + (size_t)5120 * 4096, 4096, 1024);
  transpose_cast_kernel<<<dim3(64, 64), 256, 0, stream>>>(Wo, woT, 4096, 4096);

  gemm_bt<u16><<<dim3(48, 32), 256, 0, stream>>>(xb, wqkvT, qkv, 4096, 6144, 4096, 6144);

  rope_kernel<<<40960, 256, 0, stream>>>(qkv);
  vtrans_kernel<<<dim3(32, 2, 16), 256, 0, stream>>>(qkv, vt);

  attn_kernel<<<dim3(16, 64), 256, 0, stream>>>(qkv, vt, ctx);

  gemm_bt<float><<<dim3(32, 32), 256, 0, stream>>>(ctx, woT, out, 4096, 4096, 4096, 4096);
}

// Round 6
// 878.297 us; speedup vs baseline: 1.3721x; 1.0792x over previous
//
#include <hip/hip_runtime.h>
#include <hip/hip_bf16.h>

#define T_SEQ 2048
#define NH 32
#define NKV 8
#define DH 128

typedef unsigned short u16;
typedef unsigned int u32;
typedef __attribute__((ext_vector_type(8))) short short8;
typedef __attribute__((ext_vector_type(4))) float floatx4;

union U8 { u16 s[8]; uint4 v; };
union F8 { u32 d[4]; short8 s; };

__device__ inline u16 f2bf(float f) {
  __hip_bfloat16 h = __float2bfloat16(f);
  return *reinterpret_cast<u16*>(&h);
}
__device__ inline float bf2f(u16 u) {
  __hip_bfloat16 h;
  *reinterpret_cast<u16*>(&h) = u;
  return __bfloat162float(h);
}

__device__ inline void store_out(float* p, float v) { *p = v; }
__device__ inline void store_out(u16* p, float v) { *p = f2bf(v); }

#define GLD_LDS(g, l) __builtin_amdgcn_global_load_lds( \
    (const __attribute__((address_space(1))) void*)(g), \
    (__attribute__((address_space(3))) void*)(l), 16, 0, 0)

// ---------------- cast x -> bf16 ----------------
__global__ void cast_x_kernel(const float* __restrict__ in, u16* __restrict__ out, int n8) {
  int idx = blockIdx.x * blockDim.x + threadIdx.x;
  if (idx >= n8) return;
  const float4* p = reinterpret_cast<const float4*>(in) + (size_t)idx * 2;
  float4 f0 = p[0], f1 = p[1];
  U8 u;
  u.s[0] = f2bf(f0.x); u.s[1] = f2bf(f0.y); u.s[2] = f2bf(f0.z); u.s[3] = f2bf(f0.w);
  u.s[4] = f2bf(f1.x); u.s[5] = f2bf(f1.y); u.s[6] = f2bf(f1.z); u.s[7] = f2bf(f1.w);
  *reinterpret_cast<uint4*>(out + (size_t)idx * 8) = u.v;
}

// ---------------- transpose + cast: W (K,N) f32 -> WT (N,K) bf16 ----------------
__global__ void transpose_cast_kernel(const float* __restrict__ W, u16* __restrict__ WT,
                                      int K, int N) {
  __shared__ u16 tile[64][72];
  int tid = threadIdx.x;
  int n0 = blockIdx.x * 64, k0 = blockIdx.y * 64;
  int r = tid >> 2, seg = (tid & 3) * 16;
  const float* wp = W + (size_t)(k0 + r) * N + n0 + seg;
#pragma unroll
  for (int jj = 0; jj < 4; ++jj) {
    float4 f = *(const float4*)(wp + jj * 4);
    tile[r][seg + jj * 4 + 0] = f2bf(f.x);
    tile[r][seg + jj * 4 + 1] = f2bf(f.y);
    tile[r][seg + jj * 4 + 2] = f2bf(f.z);
    tile[r][seg + jj * 4 + 3] = f2bf(f.w);
  }
  __syncthreads();
  u16* op = WT + (size_t)(n0 + r) * K + k0 + seg;
#pragma unroll
  for (int jj = 0; jj < 4; ++jj) {
    ushort4 o;
    o.x = tile[seg + jj * 4 + 0][r];
    o.y = tile[seg + jj * 4 + 1][r];
    o.z = tile[seg + jj * 4 + 2][r];
    o.w = tile[seg + jj * 4 + 3][r];
    *(ushort4*)(op + jj * 4) = o;
  }
}

// ---------------- RoPE in place on qkv rows (stride 6144) ----------------
__global__ void rope_kernel(u16* __restrict__ qkv) {
  int idx = blockIdx.x * blockDim.x + threadIdx.x;
  int i = idx & 63;
  int head = (idx >> 6) % 40;
  int row = idx / (64 * 40);
  int t = row & (T_SEQ - 1);
  int col = head < 32 ? head * 128 : 4096 + (head - 32) * 128;
  size_t base = (size_t)row * 6144 + col;
  float x1 = bf2f(qkv[base + i]);
  float x2 = bf2f(qkv[base + 64 + i]);
  float inv = exp2f(-(float)i * (18.931568569324174f / 64.0f));
  float ang = (float)t * inv;
  float c = cosf(ang), s = sinf(ang);
  qkv[base + i]      = f2bf(x1 * c - x2 * s);
  qkv[base + 64 + i] = f2bf(x1 * s + x2 * c);
}

// ---------------- V transpose ----------------
__global__ void vtrans_kernel(const u16* __restrict__ qkv, u16* __restrict__ vt) {
  __shared__ u16 tile[64][72];
  int tid = threadIdx.x;
  int t0 = blockIdx.x * 64, d0 = blockIdx.y * 64, bg = blockIdx.z;
  int b = bg >> 3, g = bg & 7;
  int r = tid >> 2, seg = (tid & 3) * 16;
  const u16* src = qkv + (size_t)(b * T_SEQ + t0 + r) * 6144 + 5120 + g * 128 + d0 + seg;
  *(uint4*)&tile[r][seg] = *(const uint4*)src;
  *(uint4*)&tile[r][seg + 8] = *(const uint4*)(src + 8);
  __syncthreads();
  u16* dst = vt + (size_t)(bg * 128 + d0 + r) * T_SEQ + t0 + seg;
  U8 o0, o1;
#pragma unroll
  for (int e = 0; e < 8; ++e) o0.s[e] = tile[seg + e][r];
#pragma unroll
  for (int e = 0; e < 8; ++e) o1.s[e] = tile[seg + 8 + e][r];
  *(uint4*)dst = o0.v;
  *(uint4*)(dst + 8) = o1.v;
}

// ---------------- GEMM (m97-class, unchanged) ----------------
template <typename OutT>
__global__ __launch_bounds__(256) void gemm_bt(const u16* __restrict__ A,
                                               const u16* __restrict__ B,
                                               OutT* __restrict__ C,
                                               int M, int N, int Kd, int ldc) {
  __shared__ u16 As[128 * 64];
  __shared__ u16 Bs[128 * 64];
  int tid = threadIdx.x;
  int wave = tid >> 6, lane = tid & 63;
  int l15 = lane & 15, quad = lane >> 4;
  int wr = wave >> 1, wc = wave & 1;
  int m0 = blockIdx.y * 128, n0 = blockIdx.x * 128;

  floatx4 acc[4][4];
#pragma unroll
  for (int mt = 0; mt < 4; ++mt)
#pragma unroll
    for (int nt = 0; nt < 4; ++nt)
#pragma unroll
      for (int r = 0; r < 4; ++r) acc[mt][nt][r] = 0.0f;

  int rloc = lane >> 3, slot = lane & 7;
  const u16* agp = A + (size_t)(m0 + wave * 32 + rloc) * Kd + ((slot ^ rloc) * 8);
  const u16* bgp = B + (size_t)(n0 + wave * 32 + rloc) * Kd + ((slot ^ rloc) * 8);
  u16* alp = As + (wave * 32) * 64;
  u16* blp = Bs + (wave * 32) * 64;

  for (int kt = 0; kt < Kd; kt += 64) {
    __syncthreads();
#pragma unroll
    for (int j = 0; j < 4; ++j) {
      GLD_LDS(agp + kt + (size_t)j * 8 * Kd, alp + j * 8 * 64);
      GLD_LDS(bgp + kt + (size_t)j * 8 * Kd, blp + j * 8 * 64);
    }
    __syncthreads();
#pragma unroll
    for (int ks = 0; ks < 2; ++ks) {
      short8 af[4], bfr[4];
      int sl = ((ks * 4 + quad) ^ (l15 & 7)) * 8;
#pragma unroll
      for (int mt = 0; mt < 4; ++mt)
        af[mt] = *(const short8*)&As[(wr * 64 + mt * 16 + l15) * 64 + sl];
#pragma unroll
      for (int nt = 0; nt < 4; ++nt)
        bfr[nt] = *(const short8*)&Bs[(wc * 64 + nt * 16 + l15) * 64 + sl];
#pragma unroll
      for (int mt = 0; mt < 4; ++mt)
#pragma unroll
        for (int nt = 0; nt < 4; ++nt)
          acc[mt][nt] = __builtin_amdgcn_mfma_f32_16x16x32_bf16(af[mt], bfr[nt], acc[mt][nt], 0, 0, 0);
    }
  }

#pragma unroll
  for (int mt = 0; mt < 4; ++mt)
#pragma unroll
    for (int nt = 0; nt < 4; ++nt)
#pragma unroll
      for (int r = 0; r < 4; ++r) {
        int rr = m0 + wr * 64 + mt * 16 + quad * 4 + r;
        int cc = n0 + wc * 64 + nt * 16 + l15;
        store_out(&C[(size_t)rr * ldc + cc], acc[mt][nt][r]);
      }
}

// ---------------- flash attention v7 ----------------
// v7 = v6 + XCD-locality block swizzle (T1 adapted): default mapping puts all 16
// (b,g) K/V streams (16 MB) on EVERY XCD's 4 MB L2 -> misses to LLC each iter.
// New bijective mapping: (b,g) pair p -> XCD p%8 (assuming round-robin id%8->XCD),
// so each XCD serves 2 pairs = 2 MB K+V, L2-resident and shared by 64 blocks.
// Heaviest tiles (bx=0) still dispatched first. Kernel internals identical to v6.
__device__ inline void softmax_frags(floatx4* sc, float& m_s, float& ell_s,
                                     floatx4* o, F8* pf,
                                     int qglob, int k0, bool diag,
                                     int l15, int quad) {
  const float C = 0.12751553f;  // (1/sqrt(128)) * log2(e)
  float s[4][4];
#pragma unroll
  for (int t4 = 0; t4 < 4; ++t4)
#pragma unroll
    for (int r = 0; r < 4; ++r) {
      float v = sc[t4][r];  // raw (unscaled) score
      if (diag && (k0 + t4 * 16 + quad * 4 + r > qglob)) v = -1e30f;
      s[t4][r] = v;
    }
  // per-q-column max (max over kk): reduce over quads
  float m = s[0][0];
#pragma unroll
  for (int t4 = 0; t4 < 4; ++t4)
#pragma unroll
    for (int r = 0; r < 4; ++r) m = fmaxf(m, s[t4][r]);
  m = fmaxf(m, __shfl_xor(m, 16));
  m = fmaxf(m, __shfl_xor(m, 32));
  // T13 defer-max: skip O/ell rescale while growth <= 90.5 raw units (p <= e^8)
  if (!__all(m <= m_s + 90.5f)) {
    float mnew = fmaxf(m_s, m);
    float alpha = __builtin_amdgcn_exp2f((m_s - mnew) * C);
    m_s = mnew;
    ell_s *= alpha;
#pragma unroll
    for (int dt = 0; dt < 8; ++dt)
#pragma unroll
      for (int r = 0; r < 4; ++r) o[dt][r] *= alpha;
  }
  float mC = m_s * C;
  float sum = 0.f;
#pragma unroll
  for (int t4 = 0; t4 < 4; ++t4)
#pragma unroll
    for (int r = 0; r < 4; ++r) {
      float p = __builtin_amdgcn_exp2f(__builtin_fmaf(s[t4][r], C, -mC));
      s[t4][r] = p;
      sum += p;
    }
  sum += __shfl_xor(sum, 16);
  sum += __shfl_xor(sum, 32);
  ell_s += sum;

  // pack P^T rows into bf16x2 dwords: pk[t4][i] = (p[2i], p[2i+1])
  u32 pk[4][2];
#pragma unroll
  for (int t4 = 0; t4 < 4; ++t4) {
    pk[t4][0] = (u32)f2bf(s[t4][0]) | ((u32)f2bf(s[t4][1]) << 16);
    pk[t4][1] = (u32)f2bf(s[t4][2]) | ((u32)f2bf(s[t4][3]) << 16);
  }
  // assemble B-operand frags: frag[h] elem j = P^T[h*32+quad*8+j][l15]
  int sidxA = (2 * (quad & 1)) * 16 + l15;
  int sidxB = sidxA + 16;
  bool hiq = (quad & 2) != 0;
#pragma unroll
  for (int h = 0; h < 2; ++h) {
    u32 a0 = __shfl((int)pk[2 * h][0], sidxA), b0 = __shfl((int)pk[2 * h + 1][0], sidxA);
    u32 a1 = __shfl((int)pk[2 * h][1], sidxA), b1 = __shfl((int)pk[2 * h + 1][1], sidxA);
    u32 a2 = __shfl((int)pk[2 * h][0], sidxB), b2 = __shfl((int)pk[2 * h + 1][0], sidxB);
    u32 a3 = __shfl((int)pk[2 * h][1], sidxB), b3 = __shfl((int)pk[2 * h + 1][1], sidxB);
    pf[h].d[0] = hiq ? b0 : a0;
    pf[h].d[1] = hiq ? b1 : a1;
    pf[h].d[2] = hiq ? b2 : a2;
    pf[h].d[3] = hiq ? b3 : a3;
  }
}

__global__ __launch_bounds__(256, 2) void attn_kernel(const u16* __restrict__ qkv,
                                                      const u16* __restrict__ vt,
                                                      u16* __restrict__ CTX) {
  // XCD-locality swizzle: id -> (b, g, head-in-group, bx), bijective over 1024.
  // XCD = id%8 hosts (b,g) pairs {xcd, xcd+8}; bx ascends with dispatch order.
  const int id  = blockIdx.x + (blockIdx.y << 4);
  const int xcd = id & 7;
  const int qq  = id >> 3;             // 0..127
  const int p   = xcd + ((qq & 1) << 3);  // (b,g) pair 0..15
  const int j   = qq >> 1;             // 0..63
  const int b   = p >> 3;
  const int g   = p & 7;
  const int h   = g * 4 + (j & 3);
  const int bx  = j >> 2;              // 0..15, heaviest (0) first
  const int bg  = b * NKV + g;
  const int tid = threadIdx.x;
  const int w = tid >> 6, lane = tid & 63;
  const int l15 = lane & 15, quad = lane >> 4;
  const int lo = bx, hi = 31 - bx;
  const int niter = hi + 1;

  __shared__ u16 Ks[2 * 64 * 128];   // [kk][d] swizzled, dbuf (32 KiB total)

  const u16* kbase = qkv + (size_t)(b * T_SEQ) * 6144 + 4096 + g * 128;
  const u16* vbase = vt + (size_t)(bg * 128) * T_SEQ;

  // Q B-operand fragments (lane holds q = l15's row)
  short8 aq[2][4];
  const int qg_lo = lo * 64 + w * 16 + l15;
  const int qg_hi = hi * 64 + w * 16 + l15;
  {
    const u16* qp0 = qkv + (size_t)(b * T_SEQ + qg_lo) * 6144 + h * 128;
    const u16* qp1 = qkv + (size_t)(b * T_SEQ + qg_hi) * 6144 + h * 128;
#pragma unroll
    for (int ks = 0; ks < 4; ++ks) {
      aq[0][ks] = *(const short8*)(qp0 + ks * 32 + quad * 8);
      aq[1][ks] = *(const short8*)(qp1 + ks * 32 + quad * 8);
    }
  }

  float m_s[2] = {-1e30f, -1e30f}, ell[2] = {0.f, 0.f};
  floatx4 o[2][8];
#pragma unroll
  for (int t = 0; t < 2; ++t)
#pragma unroll
    for (int dt = 0; dt < 8; ++dt)
#pragma unroll
      for (int r = 0; r < 4; ++r) o[t][dt][r] = 0.0f;

  // K staging lane roles
  const int krloc = lane >> 4, kslot = lane & 15;

  // prologue: stage K tile 0 into buf 0
  {
#pragma unroll
    for (int j2 = 0; j2 < 4; ++j2) {
      int rk = w * 16 + j2 * 4 + krloc;
      int gck = (kslot & 8) | ((kslot & 7) ^ (rk & 7));
      GLD_LDS(kbase + (size_t)rk * 6144 + gck * 8, Ks + (w * 16 + j2 * 4) * 128);
    }
  }

  for (int kt = 0; kt < niter; ++kt) {
    const int buf = kt & 1;
    const int k0 = kt * 64;
    __syncthreads();  // K stage(kt) complete; all waves done reading buf^1 from kt-1

    if (kt + 1 < niter) {  // prefetch K(kt+1) into buf^1, overlapped with compute(kt)
      const int nb = buf ^ 1;
      const int k0n = k0 + 64;
#pragma unroll
      for (int j2 = 0; j2 < 4; ++j2) {
        int rk = w * 16 + j2 * 4 + krloc;
        int gck = (kslot & 8) | ((kslot & 7) ^ (rk & 7));
        GLD_LDS(kbase + (size_t)(k0n + rk) * 6144 + gck * 8,
                Ks + nb * 8192 + (w * 16 + j2 * 4) * 128);
      }
    }

    const u16* Ksb = Ks + buf * 8192;
    const bool lo_on = (kt <= lo);

    // S^T = K Q^T
    floatx4 s0[4], s1[4];
#pragma unroll
    for (int t4 = 0; t4 < 4; ++t4)
#pragma unroll
      for (int r = 0; r < 4; ++r) { s0[t4][r] = 0.f; s1[t4][r] = 0.f; }

    if (lo_on) {
#pragma unroll
      for (int ks = 0; ks < 4; ++ks) {
        int c = ks * 4 + quad;
        int sl = ((c & 8) | ((c & 7) ^ (l15 & 7))) * 8;
#pragma unroll
        for (int t4 = 0; t4 < 4; ++t4) {
          short8 bk = *(const short8*)&Ksb[(t4 * 16 + l15) * 128 + sl];
          s1[t4] = __builtin_amdgcn_mfma_f32_16x16x32_bf16(bk, aq[1][ks], s1[t4], 0, 0, 0);
          s0[t4] = __builtin_amdgcn_mfma_f32_16x16x32_bf16(bk, aq[0][ks], s0[t4], 0, 0, 0);
        }
      }
    } else {
#pragma unroll
      for (int ks = 0; ks < 4; ++ks) {
        int c = ks * 4 + quad;
        int sl = ((c & 8) | ((c & 7) ^ (l15 & 7))) * 8;
#pragma unroll
        for (int t4 = 0; t4 < 4; ++t4) {
          short8 bk = *(const short8*)&Ksb[(t4 * 16 + l15) * 128 + sl];
          s1[t4] = __builtin_amdgcn_mfma_f32_16x16x32_bf16(bk, aq[1][ks], s1[t4], 0, 0, 0);
        }
      }
    }

    // softmax for both tiles -> P^T fragments
    F8 pf1[2], pf0[2];
    softmax_frags(s1, m_s[1], ell[1], o[1], pf1, qg_hi, k0, kt == hi, l15, quad);
    if (lo_on)
      softmax_frags(s0, m_s[0], ell[0], o[0], pf0, qg_lo, k0, kt == lo, l15, quad);

    // fused PV: O^T += V^T P^T; V^T fragments read directly from global (L2-hot),
    // one read shared by both q-tiles. lane reads V^T[dt*16+l15][k0 + quad*8 (+32)].
    const u16* vp0 = vbase + (size_t)l15 * T_SEQ + k0 + quad * 8;
    if (lo_on) {
#pragma unroll
      for (int dt = 0; dt < 8; ++dt) {
        const u16* vp = vp0 + (size_t)(dt * 16) * T_SEQ;
        short8 va0 = *(const short8*)vp;
        short8 va1 = *(const short8*)(vp + 32);
        o[1][dt] = __builtin_amdgcn_mfma_f32_16x16x32_bf16(va0, pf1[0].s, o[1][dt], 0, 0, 0);
        o[1][dt] = __builtin_amdgcn_mfma_f32_16x16x32_bf16(va1, pf1[1].s, o[1][dt], 0, 0, 0);
        o[0][dt] = __builtin_amdgcn_mfma_f32_16x16x32_bf16(va0, pf0[0].s, o[0][dt], 0, 0, 0);
        o[0][dt] = __builtin_amdgcn_mfma_f32_16x16x32_bf16(va1, pf0[1].s, o[0][dt], 0, 0, 0);
      }
    } else {
#pragma unroll
      for (int dt = 0; dt < 8; ++dt) {
        const u16* vp = vp0 + (size_t)(dt * 16) * T_SEQ;
        short8 va0 = *(const short8*)vp;
        short8 va1 = *(const short8*)(vp + 32);
        o[1][dt] = __builtin_amdgcn_mfma_f32_16x16x32_bf16(va0, pf1[0].s, o[1][dt], 0, 0, 0);
        o[1][dt] = __builtin_amdgcn_mfma_f32_16x16x32_bf16(va1, pf1[1].s, o[1][dt], 0, 0, 0);
      }
    }
  }

  // epilogue: O^T -> ctx (lane q = l15; 4 consecutive d per dt)
#pragma unroll
  for (int t = 0; t < 2; ++t) {
    float inv_l = 1.0f / ell[t];
    int qglob = (t ? qg_hi : qg_lo);
    u16* cp = CTX + (size_t)(b * T_SEQ + qglob) * 4096 + h * 128 + quad * 4;
#pragma unroll
    for (int dt = 0; dt < 8; ++dt) {
      ushort4 pkd;
      pkd.x = f2bf(o[t][dt][0] * inv_l);
      pkd.y = f2bf(o[t][dt][1] * inv_l);
      pkd.z = f2bf(o[t][dt][2] * inv_l);
      pkd.w = f2bf(o[t][dt][3] * inv_l);
      *(ushort4*)(cp + dt * 16) = pkd;
    }
  }
}

// ---------------- launcher ----------------
extern "C" void kernel_launch(void* const* d_in, const int* in_sizes, int n_in,
                              void* d_out, int out_size, void* d_ws, size_t ws_size,
                              hipStream_t stream) {
  const float* x  = (const float*)d_in[0];
  const float* Wq = (const float*)d_in[1];
  const float* Wk = (const float*)d_in[2];
  const float* Wv = (const float*)d_in[3];
  const float* Wo = (const float*)d_in[4];
  float* out = (float*)d_out;

  char* ws = (char*)d_ws;
  const size_t SZ_X    = (size_t)4096 * 4096 * 2;
  const size_t SZ_QKVW = (size_t)6144 * 4096 * 2;
  u16* xb    = (u16*)(ws);
  u16* wqkvT = (u16*)(ws + SZ_X);
  u16* woT   = (u16*)(ws + SZ_X + SZ_QKVW);
  u16* qkv   = (u16*)(ws + SZ_X + SZ_QKVW + SZ_X);
  u16* vt    = (u16*)(ws + SZ_X + SZ_QKVW + SZ_X + SZ_QKVW);
  u16* ctx   = xb;  // x dead after QKV GEMM

  cast_x_kernel<<<8192, 256, 0, stream>>>(x, xb, 2097152);
  transpose_cast_kernel<<<dim3(64, 64), 256, 0, stream>>>(Wq, wqkvT, 4096, 4096);
  transpose_cast_kernel<<<dim3(16, 64), 256, 0, stream>>>(Wk, wqkvT + (size_t)4096 * 4096, 4096, 1024);
  transpose_cast_kernel<<<dim3(16, 64), 256, 0, stream>>>(Wv, wqkvT + (size_t)5120 * 4096, 4096, 1024);
  transpose_cast_kernel<<<dim3(64, 64), 256, 0, stream>>>(Wo, woT, 4096, 4096);

  gemm_bt<u16><<<dim3(48, 32), 256, 0, stream>>>(xb, wqkvT, qkv, 4096, 6144, 4096, 6144);

  rope_kernel<<<40960, 256, 0, stream>>>(qkv);
  vtrans_kernel<<<dim3(32, 2, 16), 256, 0, stream>>>(qkv, vt);

  attn_kernel<<<dim3(16, 64), 256, 0, stream>>>(qkv, vt, ctx);

  gemm_bt<float><<<dim3(32, 32), 256, 0, stream>>>(ctx, woT, out, 4096, 4096, 4096, 4096);
}

// Round 7
// 870.104 us; speedup vs baseline: 1.3851x; 1.0094x over previous
//
#include <hip/hip_runtime.h>
#include <hip/hip_bf16.h>

#define T_SEQ 2048
#define NH 32
#define NKV 8
#define DH 128

typedef unsigned short u16;
typedef unsigned int u32;
typedef __attribute__((ext_vector_type(8))) short short8;
typedef __attribute__((ext_vector_type(4))) float floatx4;

union U8 { u16 s[8]; uint4 v; };
union F8 { u32 d[4]; short8 s; };

__device__ inline u16 f2bf(float f) {
  __hip_bfloat16 h = __float2bfloat16(f);
  return *reinterpret_cast<u16*>(&h);
}
__device__ inline float bf2f(u16 u) {
  __hip_bfloat16 h;
  *reinterpret_cast<u16*>(&h) = u;
  return __bfloat162float(h);
}

__device__ inline void store_out(float* p, float v) { *p = v; }
__device__ inline void store_out(u16* p, float v) { *p = f2bf(v); }

#define GLD_LDS(g, l) __builtin_amdgcn_global_load_lds( \
    (const __attribute__((address_space(1))) void*)(g), \
    (__attribute__((address_space(3))) void*)(l), 16, 0, 0)

// ---------------- fused prep: cast x + 4 transpose_casts ----------------
// blockIdx.x ranges: [0,8192) cast_x; [8192,12288) Wq; [12288,13312) Wk;
// [13312,14336) Wv; [14336,18432) Wo. Bodies identical to the former kernels.
__global__ void prep_kernel(const float* __restrict__ x, u16* __restrict__ xb,
                            const float* __restrict__ Wq, const float* __restrict__ Wk,
                            const float* __restrict__ Wv, const float* __restrict__ Wo,
                            u16* __restrict__ wqkvT, u16* __restrict__ woT) {
  __shared__ u16 tile[64][72];
  const int bid = blockIdx.x;
  const int tid = threadIdx.x;

  if (bid < 8192) {  // cast x -> bf16 (2097152 groups of 8)
    int idx = bid * 256 + tid;
    const float4* p = reinterpret_cast<const float4*>(x) + (size_t)idx * 2;
    float4 f0 = p[0], f1 = p[1];
    U8 u;
    u.s[0] = f2bf(f0.x); u.s[1] = f2bf(f0.y); u.s[2] = f2bf(f0.z); u.s[3] = f2bf(f0.w);
    u.s[4] = f2bf(f1.x); u.s[5] = f2bf(f1.y); u.s[6] = f2bf(f1.z); u.s[7] = f2bf(f1.w);
    *reinterpret_cast<uint4*>(xb + (size_t)idx * 8) = u.v;
    return;
  }

  const float* W; u16* WT; int N, local;
  const int K = 4096;
  if (bid < 12288)      { W = Wq; WT = wqkvT;                         N = 4096; local = bid - 8192; }
  else if (bid < 13312) { W = Wk; WT = wqkvT + (size_t)4096 * 4096;   N = 1024; local = bid - 12288; }
  else if (bid < 14336) { W = Wv; WT = wqkvT + (size_t)5120 * 4096;   N = 1024; local = bid - 13312; }
  else                  { W = Wo; WT = woT;                           N = 4096; local = bid - 14336; }
  const int ntiles = N >> 6;
  const int n0 = (local % ntiles) * 64, k0 = (local / ntiles) * 64;

  int r = tid >> 2, seg = (tid & 3) * 16;
  const float* wp = W + (size_t)(k0 + r) * N + n0 + seg;
#pragma unroll
  for (int jj = 0; jj < 4; ++jj) {
    float4 f = *(const float4*)(wp + jj * 4);
    tile[r][seg + jj * 4 + 0] = f2bf(f.x);
    tile[r][seg + jj * 4 + 1] = f2bf(f.y);
    tile[r][seg + jj * 4 + 2] = f2bf(f.z);
    tile[r][seg + jj * 4 + 3] = f2bf(f.w);
  }
  __syncthreads();
  u16* op = WT + (size_t)(n0 + r) * K + k0 + seg;
#pragma unroll
  for (int jj = 0; jj < 4; ++jj) {
    ushort4 o;
    o.x = tile[seg + jj * 4 + 0][r];
    o.y = tile[seg + jj * 4 + 1][r];
    o.z = tile[seg + jj * 4 + 2][r];
    o.w = tile[seg + jj * 4 + 3][r];
    *(ushort4*)(op + jj * 4) = o;
  }
}

// ---------------- fused rope + V transpose ----------------
// [0,10240): RoPE (4 pairs/thread, strided); [10240,11264): vtrans.
// Disjoint qkv ranges: rope writes cols [0,5120), vtrans reads [5120,6144).
__global__ void ropevtrans_kernel(u16* __restrict__ qkv, u16* __restrict__ vt) {
  __shared__ u16 tile[64][72];
  const int bid = blockIdx.x;
  const int tid = threadIdx.x;

  if (bid < 10240) {
    int base_idx = bid * 256 + tid;
#pragma unroll
    for (int rep = 0; rep < 4; ++rep) {
      int idx = base_idx + rep * 2621440;
      int i = idx & 63;
      int head = (idx >> 6) % 40;
      int row = idx / (64 * 40);
      int t = row & (T_SEQ - 1);
      int col = head < 32 ? head * 128 : 4096 + (head - 32) * 128;
      size_t base = (size_t)row * 6144 + col;
      float x1 = bf2f(qkv[base + i]);
      float x2 = bf2f(qkv[base + 64 + i]);
      float inv = exp2f(-(float)i * (18.931568569324174f / 64.0f));
      float ang = (float)t * inv;
      float c = cosf(ang), s = sinf(ang);
      qkv[base + i]      = f2bf(x1 * c - x2 * s);
      qkv[base + 64 + i] = f2bf(x1 * s + x2 * c);
    }
    return;
  }

  int local = bid - 10240;                 // orig grid (32, 2, 16)
  int t0 = (local & 31) * 64;
  int d0 = ((local >> 5) & 1) * 64;
  int bg = local >> 6;
  int b = bg >> 3, g = bg & 7;
  int r = tid >> 2, seg = (tid & 3) * 16;
  const u16* src = qkv + (size_t)(b * T_SEQ + t0 + r) * 6144 + 5120 + g * 128 + d0 + seg;
  *(uint4*)&tile[r][seg] = *(const uint4*)src;
  *(uint4*)&tile[r][seg + 8] = *(const uint4*)(src + 8);
  __syncthreads();
  u16* dst = vt + (size_t)(bg * 128 + d0 + r) * T_SEQ + t0 + seg;
  U8 o0, o1;
#pragma unroll
  for (int e = 0; e < 8; ++e) o0.s[e] = tile[seg + e][r];
#pragma unroll
  for (int e = 0; e < 8; ++e) o1.s[e] = tile[seg + 8 + e][r];
  *(uint4*)dst = o0.v;
  *(uint4*)(dst + 8) = o1.v;
}

// ---------------- GEMM (m97-class, unchanged) ----------------
template <typename OutT>
__global__ __launch_bounds__(256) void gemm_bt(const u16* __restrict__ A,
                                               const u16* __restrict__ B,
                                               OutT* __restrict__ C,
                                               int M, int N, int Kd, int ldc) {
  __shared__ u16 As[128 * 64];
  __shared__ u16 Bs[128 * 64];
  int tid = threadIdx.x;
  int wave = tid >> 6, lane = tid & 63;
  int l15 = lane & 15, quad = lane >> 4;
  int wr = wave >> 1, wc = wave & 1;
  int m0 = blockIdx.y * 128, n0 = blockIdx.x * 128;

  floatx4 acc[4][4];
#pragma unroll
  for (int mt = 0; mt < 4; ++mt)
#pragma unroll
    for (int nt = 0; nt < 4; ++nt)
#pragma unroll
      for (int r = 0; r < 4; ++r) acc[mt][nt][r] = 0.0f;

  int rloc = lane >> 3, slot = lane & 7;
  const u16* agp = A + (size_t)(m0 + wave * 32 + rloc) * Kd + ((slot ^ rloc) * 8);
  const u16* bgp = B + (size_t)(n0 + wave * 32 + rloc) * Kd + ((slot ^ rloc) * 8);
  u16* alp = As + (wave * 32) * 64;
  u16* blp = Bs + (wave * 32) * 64;

  for (int kt = 0; kt < Kd; kt += 64) {
    __syncthreads();
#pragma unroll
    for (int j = 0; j < 4; ++j) {
      GLD_LDS(agp + kt + (size_t)j * 8 * Kd, alp + j * 8 * 64);
      GLD_LDS(bgp + kt + (size_t)j * 8 * Kd, blp + j * 8 * 64);
    }
    __syncthreads();
#pragma unroll
    for (int ks = 0; ks < 2; ++ks) {
      short8 af[4], bfr[4];
      int sl = ((ks * 4 + quad) ^ (l15 & 7)) * 8;
#pragma unroll
      for (int mt = 0; mt < 4; ++mt)
        af[mt] = *(const short8*)&As[(wr * 64 + mt * 16 + l15) * 64 + sl];
#pragma unroll
      for (int nt = 0; nt < 4; ++nt)
        bfr[nt] = *(const short8*)&Bs[(wc * 64 + nt * 16 + l15) * 64 + sl];
#pragma unroll
      for (int mt = 0; mt < 4; ++mt)
#pragma unroll
        for (int nt = 0; nt < 4; ++nt)
          acc[mt][nt] = __builtin_amdgcn_mfma_f32_16x16x32_bf16(af[mt], bfr[nt], acc[mt][nt], 0, 0, 0);
    }
  }

#pragma unroll
  for (int mt = 0; mt < 4; ++mt)
#pragma unroll
    for (int nt = 0; nt < 4; ++nt)
#pragma unroll
      for (int r = 0; r < 4; ++r) {
        int rr = m0 + wr * 64 + mt * 16 + quad * 4 + r;
        int cc = n0 + wc * 64 + nt * 16 + l15;
        store_out(&C[(size_t)rr * ldc + cc], acc[mt][nt][r]);
      }
}

// ---------------- flash attention v7 (unchanged from R6) ----------------
__device__ inline void softmax_frags(floatx4* sc, float& m_s, float& ell_s,
                                     floatx4* o, F8* pf,
                                     int qglob, int k0, bool diag,
                                     int l15, int quad) {
  const float C = 0.12751553f;  // (1/sqrt(128)) * log2(e)
  float s[4][4];
#pragma unroll
  for (int t4 = 0; t4 < 4; ++t4)
#pragma unroll
    for (int r = 0; r < 4; ++r) {
      float v = sc[t4][r];  // raw (unscaled) score
      if (diag && (k0 + t4 * 16 + quad * 4 + r > qglob)) v = -1e30f;
      s[t4][r] = v;
    }
  float m = s[0][0];
#pragma unroll
  for (int t4 = 0; t4 < 4; ++t4)
#pragma unroll
    for (int r = 0; r < 4; ++r) m = fmaxf(m, s[t4][r]);
  m = fmaxf(m, __shfl_xor(m, 16));
  m = fmaxf(m, __shfl_xor(m, 32));
  if (!__all(m <= m_s + 90.5f)) {
    float mnew = fmaxf(m_s, m);
    float alpha = __builtin_amdgcn_exp2f((m_s - mnew) * C);
    m_s = mnew;
    ell_s *= alpha;
#pragma unroll
    for (int dt = 0; dt < 8; ++dt)
#pragma unroll
      for (int r = 0; r < 4; ++r) o[dt][r] *= alpha;
  }
  float mC = m_s * C;
  float sum = 0.f;
#pragma unroll
  for (int t4 = 0; t4 < 4; ++t4)
#pragma unroll
    for (int r = 0; r < 4; ++r) {
      float p = __builtin_amdgcn_exp2f(__builtin_fmaf(s[t4][r], C, -mC));
      s[t4][r] = p;
      sum += p;
    }
  sum += __shfl_xor(sum, 16);
  sum += __shfl_xor(sum, 32);
  ell_s += sum;

  u32 pk[4][2];
#pragma unroll
  for (int t4 = 0; t4 < 4; ++t4) {
    pk[t4][0] = (u32)f2bf(s[t4][0]) | ((u32)f2bf(s[t4][1]) << 16);
    pk[t4][1] = (u32)f2bf(s[t4][2]) | ((u32)f2bf(s[t4][3]) << 16);
  }
  int sidxA = (2 * (quad & 1)) * 16 + l15;
  int sidxB = sidxA + 16;
  bool hiq = (quad & 2) != 0;
#pragma unroll
  for (int h = 0; h < 2; ++h) {
    u32 a0 = __shfl((int)pk[2 * h][0], sidxA), b0 = __shfl((int)pk[2 * h + 1][0], sidxA);
    u32 a1 = __shfl((int)pk[2 * h][1], sidxA), b1 = __shfl((int)pk[2 * h + 1][1], sidxA);
    u32 a2 = __shfl((int)pk[2 * h][0], sidxB), b2 = __shfl((int)pk[2 * h + 1][0], sidxB);
    u32 a3 = __shfl((int)pk[2 * h][1], sidxB), b3 = __shfl((int)pk[2 * h + 1][1], sidxB);
    pf[h].d[0] = hiq ? b0 : a0;
    pf[h].d[1] = hiq ? b1 : a1;
    pf[h].d[2] = hiq ? b2 : a2;
    pf[h].d[3] = hiq ? b3 : a3;
  }
}

__global__ __launch_bounds__(256, 2) void attn_kernel(const u16* __restrict__ qkv,
                                                      const u16* __restrict__ vt,
                                                      u16* __restrict__ CTX) {
  // XCD-locality swizzle: id -> (b, g, head-in-group, bx), bijective over 1024.
  const int id  = blockIdx.x + (blockIdx.y << 4);
  const int xcd = id & 7;
  const int qq  = id >> 3;
  const int p   = xcd + ((qq & 1) << 3);
  const int j   = qq >> 1;
  const int b   = p >> 3;
  const int g   = p & 7;
  const int h   = g * 4 + (j & 3);
  const int bx  = j >> 2;
  const int bg  = b * NKV + g;
  const int tid = threadIdx.x;
  const int w = tid >> 6, lane = tid & 63;
  const int l15 = lane & 15, quad = lane >> 4;
  const int lo = bx, hi = 31 - bx;
  const int niter = hi + 1;

  __shared__ u16 Ks[2 * 64 * 128];

  const u16* kbase = qkv + (size_t)(b * T_SEQ) * 6144 + 4096 + g * 128;
  const u16* vbase = vt + (size_t)(bg * 128) * T_SEQ;

  short8 aq[2][4];
  const int qg_lo = lo * 64 + w * 16 + l15;
  const int qg_hi = hi * 64 + w * 16 + l15;
  {
    const u16* qp0 = qkv + (size_t)(b * T_SEQ + qg_lo) * 6144 + h * 128;
    const u16* qp1 = qkv + (size_t)(b * T_SEQ + qg_hi) * 6144 + h * 128;
#pragma unroll
    for (int ks = 0; ks < 4; ++ks) {
      aq[0][ks] = *(const short8*)(qp0 + ks * 32 + quad * 8);
      aq[1][ks] = *(const short8*)(qp1 + ks * 32 + quad * 8);
    }
  }

  float m_s[2] = {-1e30f, -1e30f}, ell[2] = {0.f, 0.f};
  floatx4 o[2][8];
#pragma unroll
  for (int t = 0; t < 2; ++t)
#pragma unroll
    for (int dt = 0; dt < 8; ++dt)
#pragma unroll
      for (int r = 0; r < 4; ++r) o[t][dt][r] = 0.0f;

  const int krloc = lane >> 4, kslot = lane & 15;

  {
#pragma unroll
    for (int j2 = 0; j2 < 4; ++j2) {
      int rk = w * 16 + j2 * 4 + krloc;
      int gck = (kslot & 8) | ((kslot & 7) ^ (rk & 7));
      GLD_LDS(kbase + (size_t)rk * 6144 + gck * 8, Ks + (w * 16 + j2 * 4) * 128);
    }
  }

  for (int kt = 0; kt < niter; ++kt) {
    const int buf = kt & 1;
    const int k0 = kt * 64;
    __syncthreads();

    if (kt + 1 < niter) {
      const int nb = buf ^ 1;
      const int k0n = k0 + 64;
#pragma unroll
      for (int j2 = 0; j2 < 4; ++j2) {
        int rk = w * 16 + j2 * 4 + krloc;
        int gck = (kslot & 8) | ((kslot & 7) ^ (rk & 7));
        GLD_LDS(kbase + (size_t)(k0n + rk) * 6144 + gck * 8,
                Ks + nb * 8192 + (w * 16 + j2 * 4) * 128);
      }
    }

    const u16* Ksb = Ks + buf * 8192;
    const bool lo_on = (kt <= lo);

    floatx4 s0[4], s1[4];
#pragma unroll
    for (int t4 = 0; t4 < 4; ++t4)
#pragma unroll
      for (int r = 0; r < 4; ++r) { s0[t4][r] = 0.f; s1[t4][r] = 0.f; }

    if (lo_on) {
#pragma unroll
      for (int ks = 0; ks < 4; ++ks) {
        int c = ks * 4 + quad;
        int sl = ((c & 8) | ((c & 7) ^ (l15 & 7))) * 8;
#pragma unroll
        for (int t4 = 0; t4 < 4; ++t4) {
          short8 bk = *(const short8*)&Ksb[(t4 * 16 + l15) * 128 + sl];
          s1[t4] = __builtin_amdgcn_mfma_f32_16x16x32_bf16(bk, aq[1][ks], s1[t4], 0, 0, 0);
          s0[t4] = __builtin_amdgcn_mfma_f32_16x16x32_bf16(bk, aq[0][ks], s0[t4], 0, 0, 0);
        }
      }
    } else {
#pragma unroll
      for (int ks = 0; ks < 4; ++ks) {
        int c = ks * 4 + quad;
        int sl = ((c & 8) | ((c & 7) ^ (l15 & 7))) * 8;
#pragma unroll
        for (int t4 = 0; t4 < 4; ++t4) {
          short8 bk = *(const short8*)&Ksb[(t4 * 16 + l15) * 128 + sl];
          s1[t4] = __builtin_amdgcn_mfma_f32_16x16x32_bf16(bk, aq[1][ks], s1[t4], 0, 0, 0);
        }
      }
    }

    F8 pf1[2], pf0[2];
    softmax_frags(s1, m_s[1], ell[1], o[1], pf1, qg_hi, k0, kt == hi, l15, quad);
    if (lo_on)
      softmax_frags(s0, m_s[0], ell[0], o[0], pf0, qg_lo, k0, kt == lo, l15, quad);

    const u16* vp0 = vbase + (size_t)l15 * T_SEQ + k0 + quad * 8;
    if (lo_on) {
#pragma unroll
      for (int dt = 0; dt < 8; ++dt) {
        const u16* vp = vp0 + (size_t)(dt * 16) * T_SEQ;
        short8 va0 = *(const short8*)vp;
        short8 va1 = *(const short8*)(vp + 32);
        o[1][dt] = __builtin_amdgcn_mfma_f32_16x16x32_bf16(va0, pf1[0].s, o[1][dt], 0, 0, 0);
        o[1][dt] = __builtin_amdgcn_mfma_f32_16x16x32_bf16(va1, pf1[1].s, o[1][dt], 0, 0, 0);
        o[0][dt] = __builtin_amdgcn_mfma_f32_16x16x32_bf16(va0, pf0[0].s, o[0][dt], 0, 0, 0);
        o[0][dt] = __builtin_amdgcn_mfma_f32_16x16x32_bf16(va1, pf0[1].s, o[0][dt], 0, 0, 0);
      }
    } else {
#pragma unroll
      for (int dt = 0; dt < 8; ++dt) {
        const u16* vp = vp0 + (size_t)(dt * 16) * T_SEQ;
        short8 va0 = *(const short8*)vp;
        short8 va1 = *(const short8*)(vp + 32);
        o[1][dt] = __builtin_amdgcn_mfma_f32_16x16x32_bf16(va0, pf1[0].s, o[1][dt], 0, 0, 0);
        o[1][dt] = __builtin_amdgcn_mfma_f32_16x16x32_bf16(va1, pf1[1].s, o[1][dt], 0, 0, 0);
      }
    }
  }

#pragma unroll
  for (int t = 0; t < 2; ++t) {
    float inv_l = 1.0f / ell[t];
    int qglob = (t ? qg_hi : qg_lo);
    u16* cp = CTX + (size_t)(b * T_SEQ + qglob) * 4096 + h * 128 + quad * 4;
#pragma unroll
    for (int dt = 0; dt < 8; ++dt) {
      ushort4 pkd;
      pkd.x = f2bf(o[t][dt][0] * inv_l);
      pkd.y = f2bf(o[t][dt][1] * inv_l);
      pkd.z = f2bf(o[t][dt][2] * inv_l);
      pkd.w = f2bf(o[t][dt][3] * inv_l);
      *(ushort4*)(cp + dt * 16) = pkd;
    }
  }
}

// ---------------- launcher (10 -> 5 dispatches) ----------------
extern "C" void kernel_launch(void* const* d_in, const int* in_sizes, int n_in,
                              void* d_out, int out_size, void* d_ws, size_t ws_size,
                              hipStream_t stream) {
  const float* x  = (const float*)d_in[0];
  const float* Wq = (const float*)d_in[1];
  const float* Wk = (const float*)d_in[2];
  const float* Wv = (const float*)d_in[3];
  const float* Wo = (const float*)d_in[4];
  float* out = (float*)d_out;

  char* ws = (char*)d_ws;
  const size_t SZ_X    = (size_t)4096 * 4096 * 2;
  const size_t SZ_QKVW = (size_t)6144 * 4096 * 2;
  u16* xb    = (u16*)(ws);
  u16* wqkvT = (u16*)(ws + SZ_X);
  u16* woT   = (u16*)(ws + SZ_X + SZ_QKVW);
  u16* qkv   = (u16*)(ws + SZ_X + SZ_QKVW + SZ_X);
  u16* vt    = (u16*)(ws + SZ_X + SZ_QKVW + SZ_X + SZ_QKVW);
  u16* ctx   = xb;  // x dead after QKV GEMM

  prep_kernel<<<18432, 256, 0, stream>>>(x, xb, Wq, Wk, Wv, Wo, wqkvT, woT);

  gemm_bt<u16><<<dim3(48, 32), 256, 0, stream>>>(xb, wqkvT, qkv, 4096, 6144, 4096, 6144);

  ropevtrans_kernel<<<11264, 256, 0, stream>>>(qkv, vt);

  attn_kernel<<<dim3(16, 64), 256, 0, stream>>>(qkv, vt, ctx);

  gemm_bt<float><<<dim3(32, 32), 256, 0, stream>>>(ctx, woT, out, 4096, 4096, 4096, 4096);
}